// Round 1
// 75.386 us; speedup vs baseline: 1.0076x; 1.0076x over previous
//
#include <hip/hip_runtime.h>

// AdaptiveRankingLoss, N=8192, fp32 in / scalar fp32 out.
// mean over pairs (i<j, t_i!=t_j) of hinge(margin - sign(tdiff)*pdiff)/(1+u_i+u_j).
//
// R4 -> R5:
//  * count moved off the VALU pipe: the (tdiff!=0) v_cmp mask (already needed
//    for the weight cndmask) is reused via __ballot -> s_bcnt1_b64 + s_add
//    (SALU, free: loop is VALU-pipe-bound, issue ~15cyc < pipe ~30cyc).
//    Per-pair VALU 14 -> 12 insts (34 -> 30 pipe cycles incl. 1/4-rate rcp).
//  * dual-j inner loop with split acc0/acc1 chains: ILP + SLP v_pk_* chance.
//  * wave reduction shuffles only acc (count is wave-uniform now).
//  * window accounting (rocprof): 39.4us d_ws re-poison fill + ~20-25us of
//    ~48 tiny reset dispatches are harness-owned; pair (~7us VALU-bound) +
//    finalize (~3us) is all we control.

constexpr int TILE = 128;

__global__ __launch_bounds__(TILE) void arl_pair_kernel(
    const float* __restrict__ pred, const float* __restrict__ targ,
    const float* __restrict__ unc, int n, int nt,
    float2* __restrict__ partials)
{
    // decode compact upper-triangular tile index k -> (r, c), c >= r
    const int k = blockIdx.x;
    int r = (int)((float)nt + 0.5f - sqrtf(((float)nt + 0.5f) * ((float)nt + 0.5f)
                                           - 2.0f * (float)k));
    if (r < 0) r = 0;
    auto base = [nt](int rr) { return rr * nt - (rr * (rr - 1)) / 2; };
    while (base(r + 1) <= k) ++r;
    while (base(r) > k) --r;
    const int c = r + (k - base(r));

    const int tid = threadIdx.x;
    const int i   = r * TILE + tid;
    const int j0  = c * TILE;

    __shared__ float4 sj[TILE];   // {t, p, u, pad} per j; b128 broadcast reads
    {
        const int jg = j0 + tid;
        const bool v = jg < n;
        sj[tid] = make_float4(v ? targ[jg] : 0.0f, v ? pred[jg] : 0.0f,
                              v ? unc[jg] : 0.0f, 0.0f);
    }
    __syncthreads();

    float acc0 = 0.0f, acc1 = 0.0f;
    unsigned cnt = 0;   // wave-uniform (ballot popcount), lives in SGPR
    const bool full = (j0 + TILE <= n) && (r * TILE + TILE <= n);

    if (i < n) {
        const float pi  = pred[i];
        const float ti  = targ[i];
        const float ui1 = 1.0f + unc[i];

        if (full && r != c) {
            // off-diagonal full tile: every (i, j) pair counts if t_i != t_j
            #pragma unroll 4
            for (int jj = 0; jj < TILE; jj += 2) {
                const float4 v0 = sj[jj];
                const float4 v1 = sj[jj + 1];

                const float td0 = ti - v0.x;
                const float pd0 = pi - v0.y;
                const float m0  = __builtin_amdgcn_fmed3f(fabsf(td0), 0.1f, 1.0f);
                const float sp0 = __uint_as_float(__float_as_uint(pd0) ^
                                   (__float_as_uint(td0) & 0x80000000u));
                const float h0  = fmaxf(fmaf(m0, 0.1f, -sp0), 0.0f);
                const float w0  = __builtin_amdgcn_rcpf(ui1 + v0.z);
                const bool  u0  = (td0 != 0.0f);
                acc0 = fmaf(u0 ? w0 : 0.0f, h0, acc0);
                cnt += (unsigned)__popcll(__ballot(u0));

                const float td1 = ti - v1.x;
                const float pd1 = pi - v1.y;
                const float m1  = __builtin_amdgcn_fmed3f(fabsf(td1), 0.1f, 1.0f);
                const float sp1 = __uint_as_float(__float_as_uint(pd1) ^
                                   (__float_as_uint(td1) & 0x80000000u));
                const float h1  = fmaxf(fmaf(m1, 0.1f, -sp1), 0.0f);
                const float w1  = __builtin_amdgcn_rcpf(ui1 + v1.z);
                const bool  u1  = (td1 != 0.0f);
                acc1 = fmaf(u1 ? w1 : 0.0f, h1, acc1);
                cnt += (unsigned)__popcll(__ballot(u1));
            }
        } else if (full) {
            // diagonal full tile: additionally require j > i
            #pragma unroll 4
            for (int jj = 0; jj < TILE; jj += 2) {
                const float4 v0 = sj[jj];
                const float4 v1 = sj[jj + 1];

                const float td0 = ti - v0.x;
                const float pd0 = pi - v0.y;
                const float m0  = __builtin_amdgcn_fmed3f(fabsf(td0), 0.1f, 1.0f);
                const float sp0 = __uint_as_float(__float_as_uint(pd0) ^
                                   (__float_as_uint(td0) & 0x80000000u));
                const float h0  = fmaxf(fmaf(m0, 0.1f, -sp0), 0.0f);
                const float w0  = __builtin_amdgcn_rcpf(ui1 + v0.z);
                const bool  u0  = (td0 != 0.0f) && ((j0 + jj) > i);
                acc0 = fmaf(u0 ? w0 : 0.0f, h0, acc0);
                cnt += (unsigned)__popcll(__ballot(u0));

                const float td1 = ti - v1.x;
                const float pd1 = pi - v1.y;
                const float m1  = __builtin_amdgcn_fmed3f(fabsf(td1), 0.1f, 1.0f);
                const float sp1 = __uint_as_float(__float_as_uint(pd1) ^
                                   (__float_as_uint(td1) & 0x80000000u));
                const float h1  = fmaxf(fmaf(m1, 0.1f, -sp1), 0.0f);
                const float w1  = __builtin_amdgcn_rcpf(ui1 + v1.z);
                const bool  u1  = (td1 != 0.0f) && ((j0 + jj + 1) > i);
                acc1 = fmaf(u1 ? w1 : 0.0f, h1, acc1);
                cnt += (unsigned)__popcll(__ballot(u1));
            }
        } else {
            // ragged boundary tile (dead for n = 8192, kept for generality)
            const int jmax = (n - j0 < TILE) ? (n - j0) : TILE;
            for (int jj = 0; jj < jmax; ++jj) {
                const float4 v0 = sj[jj];
                const float td0 = ti - v0.x;
                const float pd0 = pi - v0.y;
                const float m0  = __builtin_amdgcn_fmed3f(fabsf(td0), 0.1f, 1.0f);
                const float sp0 = __uint_as_float(__float_as_uint(pd0) ^
                                   (__float_as_uint(td0) & 0x80000000u));
                const float h0  = fmaxf(fmaf(m0, 0.1f, -sp0), 0.0f);
                const float w0  = __builtin_amdgcn_rcpf(ui1 + v0.z);
                const bool  u0  = (td0 != 0.0f) && ((j0 + jj) > i) && (r != c || true);
                const bool  uu  = (td0 != 0.0f) && ((r != c) ? true : ((j0 + jj) > i)) && ((j0 + jj) > i || r != c);
                // For boundary tiles r <= c always; when r != c every j counts,
                // when r == c only j > i. Use the conservative predicate:
                const bool  use = (td0 != 0.0f) && ((r != c) || ((j0 + jj) > i));
                (void)u0; (void)uu;
                acc0 = fmaf(use ? w0 : 0.0f, h0, acc0);
                cnt += (unsigned)__popcll(__ballot(use));
            }
        }
    }

    // wave reduction: acc via shuffles; cnt is already wave-uniform
    float acc = acc0 + acc1;
    #pragma unroll
    for (int off = 32; off > 0; off >>= 1) acc += __shfl_down(acc, off);

    __shared__ float    sa[TILE / 64];
    __shared__ unsigned sc[TILE / 64];
    const int lane = tid & 63, wid = tid >> 6;
    if (lane == 0) { sa[wid] = acc; sc[wid] = cnt; }
    __syncthreads();
    if (tid == 0) {
        float a2 = 0.0f; unsigned c2 = 0;
        #pragma unroll
        for (int w = 0; w < TILE / 64; ++w) { a2 += sa[w]; c2 += sc[w]; }
        partials[k] = float2{a2, (float)c2};
    }
}

__global__ __launch_bounds__(256) void arl_finalize(
    const float2* __restrict__ partials, int nPartials, float* __restrict__ out)
{
    float a = 0.0f, c = 0.0f;
    for (int k = threadIdx.x; k < nPartials; k += 256) {
        const float2 v = partials[k];
        a += v.x; c += v.y;
    }
    for (int off = 32; off > 0; off >>= 1) {
        a += __shfl_down(a, off);
        c += __shfl_down(c, off);
    }
    __shared__ float sa[4], sc[4];
    const int lane = threadIdx.x & 63, wid = threadIdx.x >> 6;
    if (lane == 0) { sa[wid] = a; sc[wid] = c; }
    __syncthreads();
    if (threadIdx.x == 0) {
        double A = 0.0, C = 0.0;
        #pragma unroll
        for (int w = 0; w < 4; ++w) { A += (double)sa[w]; C += (double)sc[w]; }
        out[0] = (float)(A / (C > 0.0 ? C : 1.0));
    }
}

extern "C" void kernel_launch(void* const* d_in, const int* in_sizes, int n_in,
                              void* d_out, int out_size, void* d_ws, size_t ws_size,
                              hipStream_t stream) {
    const float* pred = (const float*)d_in[0];
    const float* targ = (const float*)d_in[1];
    const float* unc  = (const float*)d_in[2];
    const int n = in_sizes[0];

    const int nt = (n + TILE - 1) / TILE;          // 64 for n=8192
    const int nTiles = nt * (nt + 1) / 2;          // 2080
    float2* partials = (float2*)d_ws;              // all nTiles entries written

    arl_pair_kernel<<<nTiles, TILE, 0, stream>>>(pred, targ, unc, n, nt, partials);
    arl_finalize<<<1, 256, 0, stream>>>(partials, nTiles, (float*)d_out);
}